// Round 15
// baseline (227.850 us; speedup 1.0000x reference)
//
#include <hip/hip_runtime.h>
#include <hip/hip_bf16.h>
#include <stdint.h>

typedef __attribute__((ext_vector_type(8))) short short8;
typedef __attribute__((ext_vector_type(4))) float f32x4;
typedef unsigned short u16;
typedef unsigned int u32;

static constexpr int S = 2048;
static constexpr int H = 16;
static constexpr int HD = 64;

__device__ __forceinline__ float fast_exp2(float x){
  return __builtin_amdgcn_exp2f(x);
}

__device__ __forceinline__ u16 f2bf(float f){
  union { float f; u32 u; } x; x.f = f;
  u32 r = x.u + 0x7fffu + ((x.u >> 16) & 1u);
  return (u16)(r >> 16);
}

// packed RNE f32x2 -> bf16x2 (no builtin on gfx950; single VALU op)
__device__ __forceinline__ u32 cvt_pk_bf16(float lo, float hi){
  u32 r;
  asm("v_cvt_pk_bf16_f32 %0, %1, %2" : "=v"(r) : "v"(lo), "v"(hi));
  return r;
}

// one kernel casts x (4M elems) + 4 weight matrices (1M each) to bf16
__global__ __launch_bounds__(256) void cast_all(const float* __restrict__ x,
                                                const float* __restrict__ Wq,
                                                const float* __restrict__ Wk,
                                                const float* __restrict__ Wv,
                                                const float* __restrict__ Wo,
                                                u16* __restrict__ xb,
                                                u16* __restrict__ Wb){
  int i = (blockIdx.x * 256 + threadIdx.x) * 4;
  const float* s; u16* d; int off;
  if (i < 4194304){
    s = x; d = xb; off = i;
  } else {
    int j = i - 4194304;
    int w = j >> 20;                      // 1048576 elems per weight
    s = (w == 0) ? Wq : (w == 1) ? Wk : (w == 2) ? Wv : Wo;
    d = Wb + (w << 20);
    off = j & 1048575;
  }
  float4 v = *(const float4*)(s + off);
  ushort4 o;
  o.x = f2bf(v.x); o.y = f2bf(v.y); o.z = f2bf(v.z); o.w = f2bf(v.w);
  *(ushort4*)(d + off) = o;
}

__device__ __forceinline__ void gload_lds16(const void* g, void* lds_uniform){
  __builtin_amdgcn_global_load_lds(
      (const __attribute__((address_space(1))) u32*)g,
      (__attribute__((address_space(3))) u32*)lds_uniform,
      16, 0, 0);
}

// QKV GEMM: C = A * W^T + bias.  A: [4096 x 1024] bf16. W: (out,in) bf16.
// 2-phase double-buffered LDS (stage t+1 before compute t, 1 barrier/K-step).
// z=0 (Q, pre-scaled by 0.125*log2e), z=1 (K) -> bf16 [B,H,S,HD];
// z=2 (V) -> bf16 [B,H,HD,S] (transposed).  grid (8,32,3), XCD-swizzled, 128x128 tile.
__global__ __launch_bounds__(256) void gemm_qkv(const u16* __restrict__ A,
                                                const u16* __restrict__ Wall,
                                                const float* __restrict__ b0p,
                                                const float* __restrict__ b1p,
                                                const float* __restrict__ b2p,
                                                u16* __restrict__ obf){
  __shared__ __align__(16) u16 As[2*128*32];   // 2 bufs x 8KB
  __shared__ __align__(16) u16 Bs[2*128*32];

  const int tid  = threadIdx.x;
  const int lane = tid & 63;
  const int wid  = tid >> 6;
  const int wm = wid >> 1, wn = wid & 1;
  const int l4 = lane >> 4, l15 = lane & 15;

  const int L = blockIdx.x + 8*blockIdx.y + 256*blockIdx.z;   // [0,768)
  const int W = (L & 7)*96 + (L >> 3);
  const int z = W >> 8;
  const int rem = W & 255;
  const int n0 = (rem & 7) * 128;
  const int m0 = (rem >> 3) * 128;

  const u16* Bw = Wall + (size_t)z * (1024*1024);
  const float* bias = (z == 0) ? b0p : ((z == 1) ? b1p : b2p);

  f32x4 acc[4][4];
  #pragma unroll
  for (int m=0;m<4;m++)
    #pragma unroll
    for (int n=0;n<4;n++) acc[m][n] = (f32x4){0.f,0.f,0.f,0.f};

  const char* Ab = (const char*)A  + (size_t)m0 * 2048;   // row stride = 1024*2B
  const char* Bb = (const char*)Bw + (size_t)n0 * 2048;
  char* AsB = (char*)As;
  char* BsB = (char*)Bs;

  int ldsu[2], row_[2], col_[2];
  #pragma unroll
  for (int p=0;p<2;p++){
    ldsu[p] = wid*1024 + p*4096;          // wave-uniform LDS byte base within 8KB buf
    int b = ldsu[p] + lane*16;            // this lane's 16B chunk
    row_[p] = b >> 6;                     // tile row (64B per row: 32 bf16)
    col_[p] = b & 63;                     // byte within row
  }

  // prologue: stage K-step 0 into buf 0
  #pragma unroll
  for (int p=0;p<2;p++){
    gload_lds16(Ab + (size_t)row_[p]*2048 + col_[p], AsB + ldsu[p]);
    gload_lds16(Bb + (size_t)row_[p]*2048 + col_[p], BsB + ldsu[p]);
  }
  __syncthreads();

  for (int kt = 0; kt < 32; ++kt){
    const int cur = kt & 1;
    if (kt + 1 < 32){
      const int nxt = cur ^ 1;
      const int kb = (kt + 1) * 64;       // next K byte offset
      #pragma unroll
      for (int p=0;p<2;p++){
        gload_lds16(Ab + (size_t)row_[p]*2048 + kb + col_[p], AsB + nxt*8192 + ldsu[p]);
        gload_lds16(Bb + (size_t)row_[p]*2048 + kb + col_[p], BsB + nxt*8192 + ldsu[p]);
      }
    }
    const u16* Asc = (const u16*)(AsB + cur*8192);
    const u16* Bsc = (const u16*)(BsB + cur*8192);

    short8 af[4], bfr[4];
    const int kcol = 8 * l4;
    #pragma unroll
    for (int m=0;m<4;m++)
      af[m] = *(const short8*)&Asc[(wm*64 + m*16 + l15)*32 + kcol];
    #pragma unroll
    for (int n=0;n<4;n++)
      bfr[n] = *(const short8*)&Bsc[(wn*64 + n*16 + l15)*32 + kcol];

    __builtin_amdgcn_s_setprio(1);
    #pragma unroll
    for (int m=0;m<4;m++)
      #pragma unroll
      for (int n=0;n<4;n++)
        acc[m][n] = __builtin_amdgcn_mfma_f32_16x16x32_bf16(af[m], bfr[n], acc[m][n], 0,0,0);
    __builtin_amdgcn_s_setprio(0);

    __syncthreads();                      // drains stage(kt+1); orders buf reuse
  }

  #pragma unroll
  for (int m=0;m<4;m++){
    const int rgb = m0 + wm*64 + m*16 + 4*l4;
    #pragma unroll
    for (int n=0;n<4;n++){
      const int cg = n0 + wn*64 + n*16 + l15;
      const float bb = bias[cg];
      const int bi = rgb >> 11, si = rgb & 2047;   // 4 rows share bi (rgb % 4 == 0)
      const int hi = cg >> 6,  hd = cg & 63;
      if (z == 2){
        // V transposed: [B,H,HD,S], pack 4 consecutive tokens -> 8B store
        u16* outz = obf + (size_t)2 * 4194304u;
        ushort4 o;
        o.x = f2bf(acc[m][n][0] + bb);
        o.y = f2bf(acc[m][n][1] + bb);
        o.z = f2bf(acc[m][n][2] + bb);
        o.w = f2bf(acc[m][n][3] + bb);
        *(ushort4*)&outz[(((size_t)(bi*16 + hi))*64 + hd)*2048 + si] = o;
      } else {
        u16* outz = obf + (size_t)z * 4194304u;
        // Q pre-scaled so attention scores are already in exp2 domain.
        const float sc = (z == 0) ? 0.18033688011112042f : 1.0f;
        #pragma unroll
        for (int r=0;r<4;r++)
          outz[(((size_t)(bi*16 + hi))*2048 + (si + r))*64 + hd] =
              f2bf((acc[m][n][r] + bb) * sc);
      }
    }
  }
}

// Output GEMM: out = AO * Wo^T + bo, fp32 [4096 x 1024].
// 64x128 tile, 2-phase double-buffered LDS, grid (8,64) = 512 blocks, XCD-swizzled.
__global__ __launch_bounds__(256) void gemm_out(const u16* __restrict__ A,
                                                const u16* __restrict__ Wo,
                                                const float* __restrict__ bo,
                                                float* __restrict__ ofp){
  __shared__ __align__(16) u16 As[2*64*32];    // 2 bufs x 4KB
  __shared__ __align__(16) u16 Bs[2*128*32];   // 2 bufs x 8KB

  const int tid  = threadIdx.x;
  const int lane = tid & 63;
  const int wid  = tid >> 6;
  const int wm = wid >> 1, wn = wid & 1;
  const int l4 = lane >> 4, l15 = lane & 15;

  const int L = blockIdx.x + 8*blockIdx.y;    // [0,512)
  const int W = (L & 7)*64 + (L >> 3);
  const int n0 = (W & 7) * 128;
  const int m0 = (W >> 3) * 64;

  f32x4 acc[2][4];
  #pragma unroll
  for (int m=0;m<2;m++)
    #pragma unroll
    for (int n=0;n<4;n++) acc[m][n] = (f32x4){0.f,0.f,0.f,0.f};

  const char* Ab = (const char*)A  + (size_t)m0 * 2048;
  const char* Bb = (const char*)Wo + (size_t)n0 * 2048;
  char* AsB = (char*)As;
  char* BsB = (char*)Bs;

  // A: 4KB = 1 round; B: 8KB = 2 rounds
  const int ldsuA = wid*1024;
  int rowA, colA;
  { int b = ldsuA + lane*16; rowA = b >> 6; colA = b & 63; }
  int ldsuB[2], rowB[2], colB[2];
  #pragma unroll
  for (int p=0;p<2;p++){
    ldsuB[p] = wid*2048 + p*1024;
    int b = ldsuB[p] + lane*16;
    rowB[p] = b >> 6; colB[p] = b & 63;
  }

  // prologue: stage K-step 0 into buf 0
  gload_lds16(Ab + (size_t)rowA*2048 + colA, AsB + ldsuA);
  #pragma unroll
  for (int p=0;p<2;p++)
    gload_lds16(Bb + (size_t)rowB[p]*2048 + colB[p], BsB + ldsuB[p]);
  __syncthreads();

  for (int kt = 0; kt < 32; ++kt){
    const int cur = kt & 1;
    if (kt + 1 < 32){
      const int nxt = cur ^ 1;
      const int kb = (kt + 1) * 64;
      gload_lds16(Ab + (size_t)rowA*2048 + kb + colA, AsB + nxt*4096 + ldsuA);
      #pragma unroll
      for (int p=0;p<2;p++)
        gload_lds16(Bb + (size_t)rowB[p]*2048 + kb + colB[p], BsB + nxt*8192 + ldsuB[p]);
    }
    const u16* Asc = (const u16*)(AsB + cur*4096);
    const u16* Bsc = (const u16*)(BsB + cur*8192);

    short8 af[2], bfr[4];
    const int kcol = 8 * l4;
    #pragma unroll
    for (int m=0;m<2;m++)
      af[m] = *(const short8*)&Asc[(wm*32 + m*16 + l15)*32 + kcol];
    #pragma unroll
    for (int n=0;n<4;n++)
      bfr[n] = *(const short8*)&Bsc[(wn*64 + n*16 + l15)*32 + kcol];

    __builtin_amdgcn_s_setprio(1);
    #pragma unroll
    for (int m=0;m<2;m++)
      #pragma unroll
      for (int n=0;n<4;n++)
        acc[m][n] = __builtin_amdgcn_mfma_f32_16x16x32_bf16(af[m], bfr[n], acc[m][n], 0,0,0);
    __builtin_amdgcn_s_setprio(0);

    __syncthreads();
  }

  #pragma unroll
  for (int m=0;m<2;m++){
    const int rgb = m0 + wm*32 + m*16 + 4*l4;
    #pragma unroll
    for (int n=0;n<4;n++){
      const int cg = n0 + wn*64 + n*16 + l15;
      const float bb = bo[cg];
      #pragma unroll
      for (int r=0;r<4;r++)
        ofp[(size_t)(rgb + r)*1024 + cg] = acc[m][n][r] + bb;
    }
  }
}

// Flash attention, swapped-QK^T, fixed-max softmax, permlane P-redistribution,
// 32 q-rows/wave + in-block KV-split.  NO LDS STAGING: K/V fragments are read
// directly from global (L2-resident: 512KB per (b,h), XCD-clustered) -> no
// in-loop barriers, no DS pipe, waves run unsynchronized until the combine.
// grid (16,32), 512 threads, 33KB LDS (combine scratch only).
__global__ __launch_bounds__(512, 4) void attn_fwd(const u16* __restrict__ Qg,
                                                   const u16* __restrict__ Kg,
                                                   const u16* __restrict__ Vtg,
                                                   u16* __restrict__ Og){
  __shared__ __align__(16) char scr[4*8192];   // combine: 4 pairs x 8KB
  __shared__ float lscr[128];

  const int tid  = threadIdx.x;
  const int lane = tid & 63;
  const int wid  = tid >> 6;                   // 0..7
  const int pair = wid & 3;                    // q-pair id
  const int half = wid >> 2;                   // kv half
  const int l4 = lane >> 4, l15 = lane & 15;

  // XCD swizzle: cluster all 16 q-blocks of each (b,h) onto one XCD (KV L2 reuse)
  const int L = blockIdx.x + 16*blockIdx.y;    // [0,512)
  const int W = (L & 7)*64 + (L >> 3);
  const int qb = W & 15;
  const int bh = W >> 4;
  const size_t hoff = (size_t)bh * (S * HD);

  // two 16-row Q fragment groups per wave (32 q-rows)
  short8 aq[2][2];
  #pragma unroll
  for (int g=0; g<2; ++g){
    const u16* qp = Qg + hoff + (size_t)(qb*128 + pair*32 + g*16 + l15) * HD;
    aq[g][0] = *(const short8*)(qp + 8*l4);
    aq[g][1] = *(const short8*)(qp + 32 + 8*l4);
  }

  const float FM = 12.0f;                      // fixed softmax ref (exp2 domain)
  float lr[2] = {0.f, 0.f};                    // per-LANE partial row sums
  f32x4 oacc[2][4];
  #pragma unroll
  for (int g=0; g<2; ++g)
    #pragma unroll
    for (int hb=0;hb<4;hb++) oacc[g][hb] = (f32x4){0.f,0.f,0.f,0.f};

  // per-lane global fragment bases (this half's kv rows [half*1024, +1024))
  // K [B,H,S,HD]: row (half*1024 + kt*64 + nb*16 + l15), 16B chunk l4 (k1 at +64B)
  const char* Kfrag = (const char*)(Kg + hoff) + (size_t)half*131072
                      + (size_t)l15*128 + l4*16;
  // Vt [B,H,HD,S]: row (hb*16 + l15) stride 4096B; col byte half*2048 + kt*128 + ks*64 + l4*16
  const char* Vfrag = (const char*)(Vtg + hoff) + half*2048
                      + (size_t)l15*4096 + l4*16;

  for (int kt = 0; kt < 16; ++kt){
    const char* Kt = Kfrag + (size_t)kt*8192;
    const char* Vt = Vfrag + (size_t)kt*128;

    // K fragments (L2) -> QK^T
    short8 k0[4], k1[4];
    #pragma unroll
    for (int nb=0;nb<4;nb++){
      k0[nb] = *(const short8*)(Kt + nb*2048);
      k1[nb] = *(const short8*)(Kt + nb*2048 + 64);
    }

    f32x4 sacc[2][4];
    __builtin_amdgcn_s_setprio(1);
    #pragma unroll
    for (int nb=0;nb<4;nb++){
      #pragma unroll
      for (int g=0; g<2; ++g){
        f32x4 zz = (f32x4){0.f,0.f,0.f,0.f};
        zz = __builtin_amdgcn_mfma_f32_16x16x32_bf16(k0[nb], aq[g][0], zz, 0,0,0);
        zz = __builtin_amdgcn_mfma_f32_16x16x32_bf16(k1[nb], aq[g][1], zz, 0,0,0);
        sacc[g][nb] = zz;
      }
    }
    __builtin_amdgcn_s_setprio(0);

    // issue V fragment loads now; their L2 latency hides under the softmax VALU
    short8 bv[2][4];
    #pragma unroll
    for (int ks=0;ks<2;ks++)
      #pragma unroll
      for (int hb=0;hb<4;hb++)
        bv[ks][hb] = *(const short8*)(Vt + hb*65536 + ks*64);

    // softmax numerators + in-register P redistribution (per group)
    short8 apg[2][2];
    #pragma unroll
    for (int g=0; g<2; ++g){
      float rs = 0.f;
      #pragma unroll
      for (int nb=0;nb<4;nb++)
        #pragma unroll
        for (int r=0;r<4;r++){
          float p = fast_exp2(sacc[g][nb][r] - FM);
          sacc[g][nb][r] = p;
          rs += p;
        }
      lr[g] += rs;

      u32 pk[4][2];
      #pragma unroll
      for (int nb=0;nb<4;nb++){
        pk[nb][0] = cvt_pk_bf16(sacc[g][nb][0], sacc[g][nb][1]);
        pk[nb][1] = cvt_pk_bf16(sacc[g][nb][2], sacc[g][nb][3]);
      }
      #pragma unroll
      for (int ks=0; ks<2; ++ks){
        u32 a0 = pk[2*ks][0],   a1 = pk[2*ks][1];
        u32 b0 = pk[2*ks+1][0], b1 = pk[2*ks+1][1];
        asm("v_permlane32_swap_b32 %0, %1" : "+v"(a0), "+v"(b0));
        asm("v_permlane32_swap_b32 %0, %1" : "+v"(a1), "+v"(b1));
        asm("v_permlane16_swap_b32 %0, %1" : "+v"(a0), "+v"(b0));
        asm("v_permlane16_swap_b32 %0, %1" : "+v"(a1), "+v"(b1));
        union { u32 u[4]; short8 s; } cvt;
        cvt.u[0] = a0; cvt.u[1] = a1; cvt.u[2] = b0; cvt.u[3] = b1;
        apg[g][ks] = cvt.s;
      }
    }

    // O += P V
    __builtin_amdgcn_s_setprio(1);
    #pragma unroll
    for (int ks=0;ks<2;ks++){
      #pragma unroll
      for (int hb=0;hb<4;hb++){
        oacc[0][hb] = __builtin_amdgcn_mfma_f32_16x16x32_bf16(apg[0][ks], bv[ks][hb], oacc[0][hb], 0,0,0);
        oacc[1][hb] = __builtin_amdgcn_mfma_f32_16x16x32_bf16(apg[1][ks], bv[ks][hb], oacc[1][hb], 0,0,0);
      }
    }
    __builtin_amdgcn_s_setprio(0);
  }

  // in-wave row-sum reduce (every lane -> full partial sum for q = g*16+l15)
  #pragma unroll
  for (int g=0; g<2; ++g){
    lr[g] += __shfl_xor(lr[g], 16, 64);
    lr[g] += __shfl_xor(lr[g], 32, 64);
  }

  // cross-half combine through LDS scratch (the only block-wide sync)
  if (half == 1){
    #pragma unroll
    for (int g=0; g<2; ++g)
      #pragma unroll
      for (int hb=0;hb<4;hb++)
        *(f32x4*)(scr + pair*8192 + (g*4+hb)*1024 + lane*16) = oacc[g][hb];
    if (lane < 16){
      lscr[pair*32 + lane]      = lr[0];
      lscr[pair*32 + 16 + lane] = lr[1];
    }
  }
  __syncthreads();

  if (half == 0){
    const int b = bh >> 4, h = bh & 15;
    #pragma unroll
    for (int g=0; g<2; ++g){
      const float lg = lr[g] + lscr[pair*32 + g*16 + l15];
      float inv[4];
      #pragma unroll
      for (int r=0;r<4;r++)
        inv[r] = 1.0f / __shfl(lg, 4*l4 + r, 64);
      #pragma unroll
      for (int hb=0;hb<4;hb++){
        f32x4 o2 = *(const f32x4*)(scr + pair*8192 + (g*4+hb)*1024 + lane*16);
        #pragma unroll
        for (int r=0;r<4;r++){
          const int si = qb*128 + pair*32 + g*16 + 4*l4 + r;
          const float v = (oacc[g][hb][r] + o2[r]) * inv[r];
          Og[(((size_t)(b*S + si))*H + h)*HD + hb*16 + l15] = f2bf(v);
        }
      }
    }
  }
}

extern "C" void kernel_launch(void* const* d_in, const int* in_sizes, int n_in,
                              void* d_out, int out_size, void* d_ws, size_t ws_size,
                              hipStream_t stream) {
  const float* x  = (const float*)d_in[0];
  const float* Wq = (const float*)d_in[1];
  const float* bq = (const float*)d_in[2];
  const float* Wk = (const float*)d_in[3];
  const float* bk = (const float*)d_in[4];
  const float* Wv = (const float*)d_in[5];
  const float* bv = (const float*)d_in[6];
  const float* Wo = (const float*)d_in[7];
  const float* bo = (const float*)d_in[8];

  char* ws = (char*)d_ws;
  // layout (bytes): xb 0..8M | Wb 8M..16M (Wq,Wk,Wv,Wo) | Q 16M | K 24M | Vt 32M | AO 40M..48M
  u16* xb  = (u16*)(ws);
  u16* Wb  = (u16*)(ws + (size_t)8*1024*1024);
  u16* QKV = (u16*)(ws + (size_t)16*1024*1024);
  u16* AO  = (u16*)(ws + (size_t)40*1024*1024);
  float* out = (float*)d_out;

  cast_all<<<8192, 256, 0, stream>>>(x, Wq, Wk, Wv, Wo, xb, Wb);

  dim3 g1(8, 32, 3);
  gemm_qkv<<<g1, 256, 0, stream>>>(xb, Wb, bq, bk, bv, QKV);

  dim3 g2(16, 32, 1);
  attn_fwd<<<g2, 512, 0, stream>>>(QKV, QKV + 4194304, QKV + 2*4194304, AO);

  dim3 g3(8, 64, 1);
  gemm_out<<<g3, 256, 0, stream>>>(AO, Wb + 3145728, bo, out);
}

// Round 16
// 122.079 us; speedup vs baseline: 1.8664x; 1.8664x over previous
//
#include <hip/hip_runtime.h>
#include <hip/hip_bf16.h>
#include <stdint.h>

typedef __attribute__((ext_vector_type(8))) short short8;
typedef __attribute__((ext_vector_type(4))) float f32x4;
typedef unsigned short u16;
typedef unsigned int u32;

static constexpr int S = 2048;
static constexpr int H = 16;
static constexpr int HD = 64;

__device__ __forceinline__ float fast_exp2(float x){
  return __builtin_amdgcn_exp2f(x);
}

__device__ __forceinline__ u16 f2bf(float f){
  union { float f; u32 u; } x; x.f = f;
  u32 r = x.u + 0x7fffu + ((x.u >> 16) & 1u);
  return (u16)(r >> 16);
}

// packed RNE f32x2 -> bf16x2 (no builtin on gfx950; single VALU op)
__device__ __forceinline__ u32 cvt_pk_bf16(float lo, float hi){
  u32 r;
  asm("v_cvt_pk_bf16_f32 %0, %1, %2" : "=v"(r) : "v"(lo), "v"(hi));
  return r;
}

// one kernel casts x (4M elems) + 4 weight matrices (1M each) to bf16
__global__ __launch_bounds__(256) void cast_all(const float* __restrict__ x,
                                                const float* __restrict__ Wq,
                                                const float* __restrict__ Wk,
                                                const float* __restrict__ Wv,
                                                const float* __restrict__ Wo,
                                                u16* __restrict__ xb,
                                                u16* __restrict__ Wb){
  int i = (blockIdx.x * 256 + threadIdx.x) * 4;
  const float* s; u16* d; int off;
  if (i < 4194304){
    s = x; d = xb; off = i;
  } else {
    int j = i - 4194304;
    int w = j >> 20;                      // 1048576 elems per weight
    s = (w == 0) ? Wq : (w == 1) ? Wk : (w == 2) ? Wv : Wo;
    d = Wb + (w << 20);
    off = j & 1048575;
  }
  float4 v = *(const float4*)(s + off);
  ushort4 o;
  o.x = f2bf(v.x); o.y = f2bf(v.y); o.z = f2bf(v.z); o.w = f2bf(v.w);
  *(ushort4*)(d + off) = o;
}

__device__ __forceinline__ void gload_lds16(const void* g, void* lds_uniform){
  __builtin_amdgcn_global_load_lds(
      (const __attribute__((address_space(1))) u32*)g,
      (__attribute__((address_space(3))) u32*)lds_uniform,
      16, 0, 0);
}

// QKV GEMM: C = A * W^T + bias.  A: [4096 x 1024] bf16. W: (out,in) bf16.
// 2-phase double-buffered LDS (stage t+1 before compute t, 1 barrier/K-step).
// z=0 (Q, pre-scaled by 0.125*log2e), z=1 (K) -> bf16 [B,H,S,HD];
// z=2 (V) -> bf16 [B,H,HD,S] (transposed).  grid (8,32,3), XCD-swizzled, 128x128 tile.
__global__ __launch_bounds__(256) void gemm_qkv(const u16* __restrict__ A,
                                                const u16* __restrict__ Wall,
                                                const float* __restrict__ b0p,
                                                const float* __restrict__ b1p,
                                                const float* __restrict__ b2p,
                                                u16* __restrict__ obf){
  __shared__ __align__(16) u16 As[2*128*32];   // 2 bufs x 8KB
  __shared__ __align__(16) u16 Bs[2*128*32];

  const int tid  = threadIdx.x;
  const int lane = tid & 63;
  const int wid  = tid >> 6;
  const int wm = wid >> 1, wn = wid & 1;
  const int l4 = lane >> 4, l15 = lane & 15;

  const int L = blockIdx.x + 8*blockIdx.y + 256*blockIdx.z;   // [0,768)
  const int W = (L & 7)*96 + (L >> 3);
  const int z = W >> 8;
  const int rem = W & 255;
  const int n0 = (rem & 7) * 128;
  const int m0 = (rem >> 3) * 128;

  const u16* Bw = Wall + (size_t)z * (1024*1024);
  const float* bias = (z == 0) ? b0p : ((z == 1) ? b1p : b2p);

  f32x4 acc[4][4];
  #pragma unroll
  for (int m=0;m<4;m++)
    #pragma unroll
    for (int n=0;n<4;n++) acc[m][n] = (f32x4){0.f,0.f,0.f,0.f};

  const char* Ab = (const char*)A  + (size_t)m0 * 2048;   // row stride = 1024*2B
  const char* Bb = (const char*)Bw + (size_t)n0 * 2048;
  char* AsB = (char*)As;
  char* BsB = (char*)Bs;

  int ldsu[2], row_[2], col_[2];
  #pragma unroll
  for (int p=0;p<2;p++){
    ldsu[p] = wid*1024 + p*4096;          // wave-uniform LDS byte base within 8KB buf
    int b = ldsu[p] + lane*16;            // this lane's 16B chunk
    row_[p] = b >> 6;                     // tile row (64B per row: 32 bf16)
    col_[p] = b & 63;                     // byte within row
  }

  // prologue: stage K-step 0 into buf 0
  #pragma unroll
  for (int p=0;p<2;p++){
    gload_lds16(Ab + (size_t)row_[p]*2048 + col_[p], AsB + ldsu[p]);
    gload_lds16(Bb + (size_t)row_[p]*2048 + col_[p], BsB + ldsu[p]);
  }
  __syncthreads();

  #pragma unroll 2
  for (int kt = 0; kt < 32; ++kt){
    const int cur = kt & 1;
    if (kt + 1 < 32){
      const int nxt = cur ^ 1;
      const int kb = (kt + 1) * 64;       // next K byte offset
      #pragma unroll
      for (int p=0;p<2;p++){
        gload_lds16(Ab + (size_t)row_[p]*2048 + kb + col_[p], AsB + nxt*8192 + ldsu[p]);
        gload_lds16(Bb + (size_t)row_[p]*2048 + kb + col_[p], BsB + nxt*8192 + ldsu[p]);
      }
    }
    const u16* Asc = (const u16*)(AsB + cur*8192);
    const u16* Bsc = (const u16*)(BsB + cur*8192);

    short8 af[4], bfr[4];
    const int kcol = 8 * l4;
    #pragma unroll
    for (int m=0;m<4;m++)
      af[m] = *(const short8*)&Asc[(wm*64 + m*16 + l15)*32 + kcol];
    #pragma unroll
    for (int n=0;n<4;n++)
      bfr[n] = *(const short8*)&Bsc[(wn*64 + n*16 + l15)*32 + kcol];

    __builtin_amdgcn_s_setprio(1);
    #pragma unroll
    for (int m=0;m<4;m++)
      #pragma unroll
      for (int n=0;n<4;n++)
        acc[m][n] = __builtin_amdgcn_mfma_f32_16x16x32_bf16(af[m], bfr[n], acc[m][n], 0,0,0);
    __builtin_amdgcn_s_setprio(0);

    __syncthreads();                      // drains stage(kt+1); orders buf reuse
  }

  #pragma unroll
  for (int m=0;m<4;m++){
    const int rgb = m0 + wm*64 + m*16 + 4*l4;
    #pragma unroll
    for (int n=0;n<4;n++){
      const int cg = n0 + wn*64 + n*16 + l15;
      const float bb = bias[cg];
      const int bi = rgb >> 11, si = rgb & 2047;   // 4 rows share bi (rgb % 4 == 0)
      const int hi = cg >> 6,  hd = cg & 63;
      if (z == 2){
        // V transposed: [B,H,HD,S], pack 4 consecutive tokens -> 8B store
        u16* outz = obf + (size_t)2 * 4194304u;
        ushort4 o;
        o.x = f2bf(acc[m][n][0] + bb);
        o.y = f2bf(acc[m][n][1] + bb);
        o.z = f2bf(acc[m][n][2] + bb);
        o.w = f2bf(acc[m][n][3] + bb);
        *(ushort4*)&outz[(((size_t)(bi*16 + hi))*64 + hd)*2048 + si] = o;
      } else {
        u16* outz = obf + (size_t)z * 4194304u;
        // Q pre-scaled so attention scores are already in exp2 domain.
        const float sc = (z == 0) ? 0.18033688011112042f : 1.0f;
        #pragma unroll
        for (int r=0;r<4;r++)
          outz[(((size_t)(bi*16 + hi))*2048 + (si + r))*64 + hd] =
              f2bf((acc[m][n][r] + bb) * sc);
      }
    }
  }
}

// Output GEMM: out = AO * Wo^T + bo, fp32 [4096 x 1024].
// 64x128 tile, 2-phase double-buffered LDS, grid (8,64) = 512 blocks, XCD-swizzled.
__global__ __launch_bounds__(256) void gemm_out(const u16* __restrict__ A,
                                                const u16* __restrict__ Wo,
                                                const float* __restrict__ bo,
                                                float* __restrict__ ofp){
  __shared__ __align__(16) u16 As[2*64*32];    // 2 bufs x 4KB
  __shared__ __align__(16) u16 Bs[2*128*32];   // 2 bufs x 8KB

  const int tid  = threadIdx.x;
  const int lane = tid & 63;
  const int wid  = tid >> 6;
  const int wm = wid >> 1, wn = wid & 1;
  const int l4 = lane >> 4, l15 = lane & 15;

  const int L = blockIdx.x + 8*blockIdx.y;    // [0,512)
  const int W = (L & 7)*64 + (L >> 3);
  const int n0 = (W & 7) * 128;
  const int m0 = (W >> 3) * 64;

  f32x4 acc[2][4];
  #pragma unroll
  for (int m=0;m<2;m++)
    #pragma unroll
    for (int n=0;n<4;n++) acc[m][n] = (f32x4){0.f,0.f,0.f,0.f};

  const char* Ab = (const char*)A  + (size_t)m0 * 2048;
  const char* Bb = (const char*)Wo + (size_t)n0 * 2048;
  char* AsB = (char*)As;
  char* BsB = (char*)Bs;

  // A: 4KB = 1 round; B: 8KB = 2 rounds
  const int ldsuA = wid*1024;
  int rowA, colA;
  { int b = ldsuA + lane*16; rowA = b >> 6; colA = b & 63; }
  int ldsuB[2], rowB[2], colB[2];
  #pragma unroll
  for (int p=0;p<2;p++){
    ldsuB[p] = wid*2048 + p*1024;
    int b = ldsuB[p] + lane*16;
    rowB[p] = b >> 6; colB[p] = b & 63;
  }

  // prologue: stage K-step 0 into buf 0
  gload_lds16(Ab + (size_t)rowA*2048 + colA, AsB + ldsuA);
  #pragma unroll
  for (int p=0;p<2;p++)
    gload_lds16(Bb + (size_t)rowB[p]*2048 + colB[p], BsB + ldsuB[p]);
  __syncthreads();

  #pragma unroll 2
  for (int kt = 0; kt < 32; ++kt){
    const int cur = kt & 1;
    if (kt + 1 < 32){
      const int nxt = cur ^ 1;
      const int kb = (kt + 1) * 64;
      gload_lds16(Ab + (size_t)rowA*2048 + kb + colA, AsB + nxt*4096 + ldsuA);
      #pragma unroll
      for (int p=0;p<2;p++)
        gload_lds16(Bb + (size_t)rowB[p]*2048 + kb + colB[p], BsB + nxt*8192 + ldsuB[p]);
    }
    const u16* Asc = (const u16*)(AsB + cur*4096);
    const u16* Bsc = (const u16*)(BsB + cur*8192);

    short8 af[2], bfr[4];
    const int kcol = 8 * l4;
    #pragma unroll
    for (int m=0;m<2;m++)
      af[m] = *(const short8*)&Asc[(wm*32 + m*16 + l15)*32 + kcol];
    #pragma unroll
    for (int n=0;n<4;n++)
      bfr[n] = *(const short8*)&Bsc[(wn*64 + n*16 + l15)*32 + kcol];

    __builtin_amdgcn_s_setprio(1);
    #pragma unroll
    for (int m=0;m<2;m++)
      #pragma unroll
      for (int n=0;n<4;n++)
        acc[m][n] = __builtin_amdgcn_mfma_f32_16x16x32_bf16(af[m], bfr[n], acc[m][n], 0,0,0);
    __builtin_amdgcn_s_setprio(0);

    __syncthreads();
  }

  #pragma unroll
  for (int m=0;m<2;m++){
    const int rgb = m0 + wm*32 + m*16 + 4*l4;
    #pragma unroll
    for (int n=0;n<4;n++){
      const int cg = n0 + wn*64 + n*16 + l15;
      const float bb = bo[cg];
      #pragma unroll
      for (int r=0;r<4;r++)
        ofp[(size_t)(rgb + r)*1024 + cg] = acc[m][n][r] + bb;
    }
  }
}

// Flash attention, swapped-QK^T, fixed-max softmax, permlane P-redistribution,
// 32 q-rows/wave + in-block KV-split: 8 waves = 4 q-pairs x 2 KV-halves.
// grid (16,32), 512 threads, 64KB LDS -> 2 blocks/CU = 4 waves/SIMD.
__global__ __launch_bounds__(512, 4) void attn_fwd(const u16* __restrict__ Qg,
                                                   const u16* __restrict__ Kg,
                                                   const u16* __restrict__ Vtg,
                                                   u16* __restrict__ Og){
  __shared__ __align__(16) u16 Ks[2*2*64*64];  // [half][buf] 8KB -> 32KB
  __shared__ __align__(16) u16 Vs[2*2*64*64];  // 32KB

  const int tid  = threadIdx.x;
  const int lane = tid & 63;
  const int wid  = tid >> 6;                   // 0..7
  const int pair = wid & 3;                    // q-pair id
  const int half = wid >> 2;                   // kv half
  const int l4 = lane >> 4, l15 = lane & 15;
  const int swz = l15 & 7;

  // XCD swizzle: cluster all 16 q-blocks of each (b,h) onto one XCD
  const int L = blockIdx.x + 16*blockIdx.y;    // [0,512)
  const int W = (L & 7)*64 + (L >> 3);
  const int qb = W & 15;
  const int bh = W >> 4;
  const size_t hoff = (size_t)bh * (S * HD);

  // two 16-row Q fragment groups per wave (32 q-rows)
  short8 aq[2][2];
  #pragma unroll
  for (int g=0; g<2; ++g){
    const u16* qp = Qg + hoff + (size_t)(qb*128 + pair*32 + g*16 + l15) * HD;
    aq[g][0] = *(const short8*)(qp + 8*l4);
    aq[g][1] = *(const short8*)(qp + 32 + 8*l4);
  }

  const float FM = 12.0f;                      // fixed softmax ref (exp2 domain)
  float lr[2] = {0.f, 0.f};                    // per-LANE partial row sums
  f32x4 oacc[2][4];
  #pragma unroll
  for (int g=0; g<2; ++g)
    #pragma unroll
    for (int hb=0;hb<4;hb++) oacc[g][hb] = (f32x4){0.f,0.f,0.f,0.f};

  // per-half global streams and LDS regions
  const char* Kb = (const char*)(Kg  + hoff) + (size_t)half*16*8192;  // 16 tiles ahead
  const char* Vb = (const char*)(Vtg + hoff) + half*16*128;           // 16*64 columns
  char* KsB = (char*)Ks + half*16384;
  char* VsB = (char*)Vs + half*16384;

  int ldsu[2], srcK[2], srcV[2];
  #pragma unroll
  for (int p=0;p<2;p++){
    ldsu[p] = pair*1024 + p*4096;              // 4 waves cover 8KB in 2 rounds
    int b   = ldsu[p] + lane*16;
    int row = b >> 7, cc = (b >> 4) & 7;
    int ccs = cc ^ (row & 7);                  // pre-swizzled source chunk
    srcK[p] = row*128  + (ccs << 4);
    srcV[p] = row*4096 + (ccs << 4);
  }

  // prologue: stage this half's tile 0 into buf 0
  #pragma unroll
  for (int p=0;p<2;p++){
    gload_lds16(Kb + srcK[p], KsB + ldsu[p]);
    gload_lds16(Vb + srcV[p], VsB + ldsu[p]);
  }
  __syncthreads();

  #pragma unroll 2
  for (int kt = 0; kt < 16; ++kt){
    const int cur = kt & 1;
    if (kt + 1 < 16){
      const int nxt = cur ^ 1;
      const char* Ksrc = Kb + (size_t)(kt+1)*8192;
      const char* Vsrc = Vb + (size_t)(kt+1)*128;
      #pragma unroll
      for (int p=0;p<2;p++){
        gload_lds16(Ksrc + srcK[p], KsB + nxt*8192 + ldsu[p]);
        gload_lds16(Vsrc + srcV[p], VsB + nxt*8192 + ldsu[p]);
      }
    }

    const char* KsC = KsB + cur*8192;
    const char* VsC = VsB + cur*8192;

    // S^T: mfma(A=K_frag, B=Q_frag); K-frags read once, shared by both q-groups
    f32x4 sacc[2][4];
    __builtin_amdgcn_s_setprio(1);
    #pragma unroll
    for (int nb=0;nb<4;nb++){
      const int krow = nb*16 + l15;
      short8 k0 = *(const short8*)(KsC + krow*128 + ((l4 ^ swz) << 4));
      short8 k1 = *(const short8*)(KsC + krow*128 + (((4 + l4) ^ swz) << 4));
      #pragma unroll
      for (int g=0; g<2; ++g){
        f32x4 zz = (f32x4){0.f,0.f,0.f,0.f};
        zz = __builtin_amdgcn_mfma_f32_16x16x32_bf16(k0, aq[g][0], zz, 0,0,0);
        zz = __builtin_amdgcn_mfma_f32_16x16x32_bf16(k1, aq[g][1], zz, 0,0,0);
        sacc[g][nb] = zz;
      }
    }
    __builtin_amdgcn_s_setprio(0);

    // softmax numerators + in-register P redistribution (per group)
    short8 apg[2][2];
    #pragma unroll
    for (int g=0; g<2; ++g){
      float rs = 0.f;
      #pragma unroll
      for (int nb=0;nb<4;nb++)
        #pragma unroll
        for (int r=0;r<4;r++){
          float p = fast_exp2(sacc[g][nb][r] - FM);
          sacc[g][nb][r] = p;
          rs += p;
        }
      lr[g] += rs;

      u32 pk[4][2];
      #pragma unroll
      for (int nb=0;nb<4;nb++){
        pk[nb][0] = cvt_pk_bf16(sacc[g][nb][0], sacc[g][nb][1]);
        pk[nb][1] = cvt_pk_bf16(sacc[g][nb][2], sacc[g][nb][3]);
      }
      #pragma unroll
      for (int ks=0; ks<2; ++ks){
        u32 a0 = pk[2*ks][0],   a1 = pk[2*ks][1];
        u32 b0 = pk[2*ks+1][0], b1 = pk[2*ks+1][1];
        asm("v_permlane32_swap_b32 %0, %1" : "+v"(a0), "+v"(b0));
        asm("v_permlane32_swap_b32 %0, %1" : "+v"(a1), "+v"(b1));
        asm("v_permlane16_swap_b32 %0, %1" : "+v"(a0), "+v"(b0));
        asm("v_permlane16_swap_b32 %0, %1" : "+v"(a1), "+v"(b1));
        union { u32 u[4]; short8 s; } cvt;
        cvt.u[0] = a0; cvt.u[1] = a1; cvt.u[2] = b0; cvt.u[3] = b1;
        apg[g][ks] = cvt.s;
      }
    }

    // O += P V  (V-frags read once, shared by both q-groups)
    __builtin_amdgcn_s_setprio(1);
    #pragma unroll
    for (int ks=0;ks<2;ks++){
      #pragma unroll
      for (int hb=0;hb<4;hb++){
        const int vrow = hb*16 + l15;
        short8 bv = *(const short8*)(VsC + vrow*128 + (((ks*4 + l4) ^ swz) << 4));
        oacc[0][hb] = __builtin_amdgcn_mfma_f32_16x16x32_bf16(apg[0][ks], bv, oacc[0][hb], 0,0,0);
        oacc[1][hb] = __builtin_amdgcn_mfma_f32_16x16x32_bf16(apg[1][ks], bv, oacc[1][hb], 0,0,0);
      }
    }
    __builtin_amdgcn_s_setprio(0);
    __syncthreads();   // drains stage(kt+1) vmem + orders buffer reuse
  }

  // in-wave row-sum reduce (every lane -> full partial sum for q = g*16+l15)
  #pragma unroll
  for (int g=0; g<2; ++g){
    lr[g] += __shfl_xor(lr[g], 16, 64);
    lr[g] += __shfl_xor(lr[g], 32, 64);
  }

  // cross-half combine through dead stage LDS
  char*  scr  = (char*)Ks;                     // 32KB: 4 pairs x 8KB
  float* lscr = (float*)Vs;                    // 128 floats
  if (half == 1){
    #pragma unroll
    for (int g=0; g<2; ++g)
      #pragma unroll
      for (int hb=0;hb<4;hb++)
        *(f32x4*)(scr + pair*8192 + (g*4+hb)*1024 + lane*16) = oacc[g][hb];
    if (lane < 16){
      lscr[pair*32 + lane]      = lr[0];
      lscr[pair*32 + 16 + lane] = lr[1];
    }
  }
  __syncthreads();

  if (half == 0){
    const int b = bh >> 4, h = bh & 15;
    #pragma unroll
    for (int g=0; g<2; ++g){
      const float lg = lr[g] + lscr[pair*32 + g*16 + l15];
      float inv[4];
      #pragma unroll
      for (int r=0;r<4;r++)
        inv[r] = 1.0f / __shfl(lg, 4*l4 + r, 64);
      #pragma unroll
      for (int hb=0;hb<4;hb++){
        f32x4 o2 = *(const f32x4*)(scr + pair*8192 + (g*4+hb)*1024 + lane*16);
        #pragma unroll
        for (int r=0;r<4;r++){
          const int si = qb*128 + pair*32 + g*16 + 4*l4 + r;
          const float v = (oacc[g][hb][r] + o2[r]) * inv[r];
          Og[(((size_t)(b*S + si))*H + h)*HD + hb*16 + l15] = f2bf(v);
        }
      }
    }
  }
}

extern "C" void kernel_launch(void* const* d_in, const int* in_sizes, int n_in,
                              void* d_out, int out_size, void* d_ws, size_t ws_size,
                              hipStream_t stream) {
  const float* x  = (const float*)d_in[0];
  const float* Wq = (const float*)d_in[1];
  const float* bq = (const float*)d_in[2];
  const float* Wk = (const float*)d_in[3];
  const float* bk = (const float*)d_in[4];
  const float* Wv = (const float*)d_in[5];
  const float* bv = (const float*)d_in[6];
  const float* Wo = (const float*)d_in[7];
  const float* bo = (const float*)d_in[8];

  char* ws = (char*)d_ws;
  // layout (bytes): xb 0..8M | Wb 8M..16M (Wq,Wk,Wv,Wo) | Q 16M | K 24M | Vt 32M | AO 40M..48M
  u16* xb  = (u16*)(ws);
  u16* Wb  = (u16*)(ws + (size_t)8*1024*1024);
  u16* QKV = (u16*)(ws + (size_t)16*1024*1024);
  u16* AO  = (u16*)(ws + (size_t)40*1024*1024);
  float* out = (float*)d_out;

  cast_all<<<8192, 256, 0, stream>>>(x, Wq, Wk, Wv, Wo, xb, Wb);

  dim3 g1(8, 32, 3);
  gemm_qkv<<<g1, 256, 0, stream>>>(xb, Wb, bq, bk, bv, QKV);

  dim3 g2(16, 32, 1);
  attn_fwd<<<g2, 512, 0, stream>>>(QKV, QKV + 4194304, QKV + 2*4194304, AO);

  dim3 g3(8, 64, 1);
  gemm_out<<<g3, 256, 0, stream>>>(AO, Wb + 3145728, bo, out);
}

// Round 17
// 113.970 us; speedup vs baseline: 1.9992x; 1.0711x over previous
//
#include <hip/hip_runtime.h>
#include <hip/hip_bf16.h>
#include <stdint.h>

typedef __attribute__((ext_vector_type(8))) short short8;
typedef __attribute__((ext_vector_type(4))) float f32x4;
typedef unsigned short u16;
typedef unsigned int u32;

static constexpr int S = 2048;
static constexpr int H = 16;
static constexpr int HD = 64;

__device__ __forceinline__ float fast_exp2(float x){
  return __builtin_amdgcn_exp2f(x);
}

__device__ __forceinline__ u16 f2bf(float f){
  union { float f; u32 u; } x; x.f = f;
  u32 r = x.u + 0x7fffu + ((x.u >> 16) & 1u);
  return (u16)(r >> 16);
}

// packed RNE f32x2 -> bf16x2 (no builtin on gfx950; single VALU op)
__device__ __forceinline__ u32 cvt_pk_bf16(float lo, float hi){
  u32 r;
  asm("v_cvt_pk_bf16_f32 %0, %1, %2" : "=v"(r) : "v"(lo), "v"(hi));
  return r;
}

// one kernel casts x (4M elems) + 4 weight matrices (1M each) to bf16
__global__ __launch_bounds__(256) void cast_all(const float* __restrict__ x,
                                                const float* __restrict__ Wq,
                                                const float* __restrict__ Wk,
                                                const float* __restrict__ Wv,
                                                const float* __restrict__ Wo,
                                                u16* __restrict__ xb,
                                                u16* __restrict__ Wb){
  int i = (blockIdx.x * 256 + threadIdx.x) * 4;
  const float* s; u16* d; int off;
  if (i < 4194304){
    s = x; d = xb; off = i;
  } else {
    int j = i - 4194304;
    int w = j >> 20;                      // 1048576 elems per weight
    s = (w == 0) ? Wq : (w == 1) ? Wk : (w == 2) ? Wv : Wo;
    d = Wb + (w << 20);
    off = j & 1048575;
  }
  float4 v = *(const float4*)(s + off);
  ushort4 o;
  o.x = f2bf(v.x); o.y = f2bf(v.y); o.z = f2bf(v.z); o.w = f2bf(v.w);
  *(ushort4*)(d + off) = o;
}

__device__ __forceinline__ void gload_lds16(const void* g, void* lds_uniform){
  __builtin_amdgcn_global_load_lds(
      (const __attribute__((address_space(1))) u32*)g,
      (__attribute__((address_space(3))) u32*)lds_uniform,
      16, 0, 0);
}

// QKV GEMM: C = A * W^T + bias.  A: [4096 x 1024] bf16. W: (out,in) bf16.
// 2-phase double-buffered LDS (stage t+1 before compute t, 1 barrier/K-step).
// z=0 (Q, pre-scaled by 0.125*log2e), z=1 (K) -> bf16 [B,H,S,HD];
// z=2 (V) -> bf16 [B,H,HD,S] (transposed).  grid (8,32,3), XCD-swizzled, 128x128 tile.
// NOTE: do NOT unroll this K-loop (r16: unroll 2 => 30->52us, schedule breaks).
__global__ __launch_bounds__(256) void gemm_qkv(const u16* __restrict__ A,
                                                const u16* __restrict__ Wall,
                                                const float* __restrict__ b0p,
                                                const float* __restrict__ b1p,
                                                const float* __restrict__ b2p,
                                                u16* __restrict__ obf){
  __shared__ __align__(16) u16 As[2*128*32];   // 2 bufs x 8KB
  __shared__ __align__(16) u16 Bs[2*128*32];

  const int tid  = threadIdx.x;
  const int lane = tid & 63;
  const int wid  = tid >> 6;
  const int wm = wid >> 1, wn = wid & 1;
  const int l4 = lane >> 4, l15 = lane & 15;

  const int L = blockIdx.x + 8*blockIdx.y + 256*blockIdx.z;   // [0,768)
  const int W = (L & 7)*96 + (L >> 3);
  const int z = W >> 8;
  const int rem = W & 255;
  const int n0 = (rem & 7) * 128;
  const int m0 = (rem >> 3) * 128;

  const u16* Bw = Wall + (size_t)z * (1024*1024);
  const float* bias = (z == 0) ? b0p : ((z == 1) ? b1p : b2p);

  f32x4 acc[4][4];
  #pragma unroll
  for (int m=0;m<4;m++)
    #pragma unroll
    for (int n=0;n<4;n++) acc[m][n] = (f32x4){0.f,0.f,0.f,0.f};

  const char* Ab = (const char*)A  + (size_t)m0 * 2048;   // row stride = 1024*2B
  const char* Bb = (const char*)Bw + (size_t)n0 * 2048;
  char* AsB = (char*)As;
  char* BsB = (char*)Bs;

  int ldsu[2], row_[2], col_[2];
  #pragma unroll
  for (int p=0;p<2;p++){
    ldsu[p] = wid*1024 + p*4096;          // wave-uniform LDS byte base within 8KB buf
    int b = ldsu[p] + lane*16;            // this lane's 16B chunk
    row_[p] = b >> 6;                     // tile row (64B per row: 32 bf16)
    col_[p] = b & 63;                     // byte within row
  }

  // prologue: stage K-step 0 into buf 0
  #pragma unroll
  for (int p=0;p<2;p++){
    gload_lds16(Ab + (size_t)row_[p]*2048 + col_[p], AsB + ldsu[p]);
    gload_lds16(Bb + (size_t)row_[p]*2048 + col_[p], BsB + ldsu[p]);
  }
  __syncthreads();

  for (int kt = 0; kt < 32; ++kt){
    const int cur = kt & 1;
    if (kt + 1 < 32){
      const int nxt = cur ^ 1;
      const int kb = (kt + 1) * 64;       // next K byte offset
      #pragma unroll
      for (int p=0;p<2;p++){
        gload_lds16(Ab + (size_t)row_[p]*2048 + kb + col_[p], AsB + nxt*8192 + ldsu[p]);
        gload_lds16(Bb + (size_t)row_[p]*2048 + kb + col_[p], BsB + nxt*8192 + ldsu[p]);
      }
    }
    const u16* Asc = (const u16*)(AsB + cur*8192);
    const u16* Bsc = (const u16*)(BsB + cur*8192);

    short8 af[4], bfr[4];
    const int kcol = 8 * l4;
    #pragma unroll
    for (int m=0;m<4;m++)
      af[m] = *(const short8*)&Asc[(wm*64 + m*16 + l15)*32 + kcol];
    #pragma unroll
    for (int n=0;n<4;n++)
      bfr[n] = *(const short8*)&Bsc[(wn*64 + n*16 + l15)*32 + kcol];

    __builtin_amdgcn_s_setprio(1);
    #pragma unroll
    for (int m=0;m<4;m++)
      #pragma unroll
      for (int n=0;n<4;n++)
        acc[m][n] = __builtin_amdgcn_mfma_f32_16x16x32_bf16(af[m], bfr[n], acc[m][n], 0,0,0);
    __builtin_amdgcn_s_setprio(0);

    __syncthreads();                      // drains stage(kt+1); orders buf reuse
  }

  #pragma unroll
  for (int m=0;m<4;m++){
    const int rgb = m0 + wm*64 + m*16 + 4*l4;
    #pragma unroll
    for (int n=0;n<4;n++){
      const int cg = n0 + wn*64 + n*16 + l15;
      const float bb = bias[cg];
      const int bi = rgb >> 11, si = rgb & 2047;   // 4 rows share bi (rgb % 4 == 0)
      const int hi = cg >> 6,  hd = cg & 63;
      if (z == 2){
        // V transposed: [B,H,HD,S], pack 4 consecutive tokens -> 8B store
        u16* outz = obf + (size_t)2 * 4194304u;
        ushort4 o;
        o.x = f2bf(acc[m][n][0] + bb);
        o.y = f2bf(acc[m][n][1] + bb);
        o.z = f2bf(acc[m][n][2] + bb);
        o.w = f2bf(acc[m][n][3] + bb);
        *(ushort4*)&outz[(((size_t)(bi*16 + hi))*64 + hd)*2048 + si] = o;
      } else {
        u16* outz = obf + (size_t)z * 4194304u;
        // Q pre-scaled so attention scores are already in exp2 domain.
        const float sc = (z == 0) ? 0.18033688011112042f : 1.0f;
        #pragma unroll
        for (int r=0;r<4;r++)
          outz[(((size_t)(bi*16 + hi))*2048 + (si + r))*64 + hd] =
              f2bf((acc[m][n][r] + bb) * sc);
      }
    }
  }
}

// Output GEMM: out = AO * Wo^T + bo, fp32 [4096 x 1024].
// 64x128 tile, 2-phase double-buffered LDS, grid (8,64) = 512 blocks, XCD-swizzled.
// NOTE: do NOT unroll this K-loop (r16 lesson).
__global__ __launch_bounds__(256) void gemm_out(const u16* __restrict__ A,
                                                const u16* __restrict__ Wo,
                                                const float* __restrict__ bo,
                                                float* __restrict__ ofp){
  __shared__ __align__(16) u16 As[2*64*32];    // 2 bufs x 4KB
  __shared__ __align__(16) u16 Bs[2*128*32];   // 2 bufs x 8KB

  const int tid  = threadIdx.x;
  const int lane = tid & 63;
  const int wid  = tid >> 6;
  const int wm = wid >> 1, wn = wid & 1;
  const int l4 = lane >> 4, l15 = lane & 15;

  const int L = blockIdx.x + 8*blockIdx.y;    // [0,512)
  const int W = (L & 7)*64 + (L >> 3);
  const int n0 = (W & 7) * 128;
  const int m0 = (W >> 3) * 64;

  f32x4 acc[2][4];
  #pragma unroll
  for (int m=0;m<2;m++)
    #pragma unroll
    for (int n=0;n<4;n++) acc[m][n] = (f32x4){0.f,0.f,0.f,0.f};

  const char* Ab = (const char*)A  + (size_t)m0 * 2048;
  const char* Bb = (const char*)Wo + (size_t)n0 * 2048;
  char* AsB = (char*)As;
  char* BsB = (char*)Bs;

  // A: 4KB = 1 round; B: 8KB = 2 rounds
  const int ldsuA = wid*1024;
  int rowA, colA;
  { int b = ldsuA + lane*16; rowA = b >> 6; colA = b & 63; }
  int ldsuB[2], rowB[2], colB[2];
  #pragma unroll
  for (int p=0;p<2;p++){
    ldsuB[p] = wid*2048 + p*1024;
    int b = ldsuB[p] + lane*16;
    rowB[p] = b >> 6; colB[p] = b & 63;
  }

  // prologue: stage K-step 0 into buf 0
  gload_lds16(Ab + (size_t)rowA*2048 + colA, AsB + ldsuA);
  #pragma unroll
  for (int p=0;p<2;p++)
    gload_lds16(Bb + (size_t)rowB[p]*2048 + colB[p], BsB + ldsuB[p]);
  __syncthreads();

  for (int kt = 0; kt < 32; ++kt){
    const int cur = kt & 1;
    if (kt + 1 < 32){
      const int nxt = cur ^ 1;
      const int kb = (kt + 1) * 64;
      gload_lds16(Ab + (size_t)rowA*2048 + kb + colA, AsB + nxt*4096 + ldsuA);
      #pragma unroll
      for (int p=0;p<2;p++)
        gload_lds16(Bb + (size_t)rowB[p]*2048 + kb + colB[p], BsB + nxt*8192 + ldsuB[p]);
    }
    const u16* Asc = (const u16*)(AsB + cur*4096);
    const u16* Bsc = (const u16*)(BsB + cur*8192);

    short8 af[2], bfr[4];
    const int kcol = 8 * l4;
    #pragma unroll
    for (int m=0;m<2;m++)
      af[m] = *(const short8*)&Asc[(wm*32 + m*16 + l15)*32 + kcol];
    #pragma unroll
    for (int n=0;n<4;n++)
      bfr[n] = *(const short8*)&Bsc[(wn*64 + n*16 + l15)*32 + kcol];

    __builtin_amdgcn_s_setprio(1);
    #pragma unroll
    for (int m=0;m<2;m++)
      #pragma unroll
      for (int n=0;n<4;n++)
        acc[m][n] = __builtin_amdgcn_mfma_f32_16x16x32_bf16(af[m], bfr[n], acc[m][n], 0,0,0);
    __builtin_amdgcn_s_setprio(0);

    __syncthreads();
  }

  #pragma unroll
  for (int m=0;m<2;m++){
    const int rgb = m0 + wm*32 + m*16 + 4*l4;
    #pragma unroll
    for (int n=0;n<4;n++){
      const int cg = n0 + wn*64 + n*16 + l15;
      const float bb = bo[cg];
      #pragma unroll
      for (int r=0;r<4;r++)
        ofp[(size_t)(rgb + r)*1024 + cg] = acc[m][n][r] + bb;
    }
  }
}

// Flash attention, swapped-QK^T, fixed-max softmax, permlane P-redistribution,
// 32 q-rows/wave + in-block KV-split: 8 waves = 4 q-pairs x 2 KV-halves.
// grid (16,32), 512 threads, 64KB LDS -> 2 blocks/CU = 4 waves/SIMD.
__global__ __launch_bounds__(512, 4) void attn_fwd(const u16* __restrict__ Qg,
                                                   const u16* __restrict__ Kg,
                                                   const u16* __restrict__ Vtg,
                                                   u16* __restrict__ Og){
  __shared__ __align__(16) u16 Ks[2*2*64*64];  // [half][buf] 8KB -> 32KB
  __shared__ __align__(16) u16 Vs[2*2*64*64];  // 32KB

  const int tid  = threadIdx.x;
  const int lane = tid & 63;
  const int wid  = tid >> 6;                   // 0..7
  const int pair = wid & 3;                    // q-pair id
  const int half = wid >> 2;                   // kv half
  const int l4 = lane >> 4, l15 = lane & 15;
  const int swz = l15 & 7;

  // XCD swizzle: cluster all 16 q-blocks of each (b,h) onto one XCD
  const int L = blockIdx.x + 16*blockIdx.y;    // [0,512)
  const int W = (L & 7)*64 + (L >> 3);
  const int qb = W & 15;
  const int bh = W >> 4;
  const size_t hoff = (size_t)bh * (S * HD);

  // two 16-row Q fragment groups per wave (32 q-rows)
  short8 aq[2][2];
  #pragma unroll
  for (int g=0; g<2; ++g){
    const u16* qp = Qg + hoff + (size_t)(qb*128 + pair*32 + g*16 + l15) * HD;
    aq[g][0] = *(const short8*)(qp + 8*l4);
    aq[g][1] = *(const short8*)(qp + 32 + 8*l4);
  }

  const float FM = 12.0f;                      // fixed softmax ref (exp2 domain)
  float lr[2] = {0.f, 0.f};                    // per-LANE partial row sums
  f32x4 oacc[2][4];
  #pragma unroll
  for (int g=0; g<2; ++g)
    #pragma unroll
    for (int hb=0;hb<4;hb++) oacc[g][hb] = (f32x4){0.f,0.f,0.f,0.f};

  // per-half global streams and LDS regions
  const char* Kb = (const char*)(Kg  + hoff) + (size_t)half*16*8192;  // 16 tiles ahead
  const char* Vb = (const char*)(Vtg + hoff) + half*16*128;           // 16*64 columns
  char* KsB = (char*)Ks + half*16384;
  char* VsB = (char*)Vs + half*16384;

  int ldsu[2], srcK[2], srcV[2];
  #pragma unroll
  for (int p=0;p<2;p++){
    ldsu[p] = pair*1024 + p*4096;              // 4 waves cover 8KB in 2 rounds
    int b   = ldsu[p] + lane*16;
    int row = b >> 7, cc = (b >> 4) & 7;
    int ccs = cc ^ (row & 7);                  // pre-swizzled source chunk
    srcK[p] = row*128  + (ccs << 4);
    srcV[p] = row*4096 + (ccs << 4);
  }

  // prologue: stage this half's tile 0 into buf 0
  #pragma unroll
  for (int p=0;p<2;p++){
    gload_lds16(Kb + srcK[p], KsB + ldsu[p]);
    gload_lds16(Vb + srcV[p], VsB + ldsu[p]);
  }
  __syncthreads();

  #pragma unroll 2
  for (int kt = 0; kt < 16; ++kt){
    const int cur = kt & 1;
    if (kt + 1 < 16){
      const int nxt = cur ^ 1;
      const char* Ksrc = Kb + (size_t)(kt+1)*8192;
      const char* Vsrc = Vb + (size_t)(kt+1)*128;
      #pragma unroll
      for (int p=0;p<2;p++){
        gload_lds16(Ksrc + srcK[p], KsB + nxt*8192 + ldsu[p]);
        gload_lds16(Vsrc + srcV[p], VsB + nxt*8192 + ldsu[p]);
      }
    }

    const char* KsC = KsB + cur*8192;
    const char* VsC = VsB + cur*8192;

    // S^T: mfma(A=K_frag, B=Q_frag); K-frags read once, shared by both q-groups
    f32x4 sacc[2][4];
    __builtin_amdgcn_s_setprio(1);
    #pragma unroll
    for (int nb=0;nb<4;nb++){
      const int krow = nb*16 + l15;
      short8 k0 = *(const short8*)(KsC + krow*128 + ((l4 ^ swz) << 4));
      short8 k1 = *(const short8*)(KsC + krow*128 + (((4 + l4) ^ swz) << 4));
      #pragma unroll
      for (int g=0; g<2; ++g){
        f32x4 zz = (f32x4){0.f,0.f,0.f,0.f};
        zz = __builtin_amdgcn_mfma_f32_16x16x32_bf16(k0, aq[g][0], zz, 0,0,0);
        zz = __builtin_amdgcn_mfma_f32_16x16x32_bf16(k1, aq[g][1], zz, 0,0,0);
        sacc[g][nb] = zz;
      }
    }
    __builtin_amdgcn_s_setprio(0);

    // softmax numerators + in-register P redistribution (per group)
    short8 apg[2][2];
    #pragma unroll
    for (int g=0; g<2; ++g){
      float rs = 0.f;
      #pragma unroll
      for (int nb=0;nb<4;nb++)
        #pragma unroll
        for (int r=0;r<4;r++){
          float p = fast_exp2(sacc[g][nb][r] - FM);
          sacc[g][nb][r] = p;
          rs += p;
        }
      lr[g] += rs;

      u32 pk[4][2];
      #pragma unroll
      for (int nb=0;nb<4;nb++){
        pk[nb][0] = cvt_pk_bf16(sacc[g][nb][0], sacc[g][nb][1]);
        pk[nb][1] = cvt_pk_bf16(sacc[g][nb][2], sacc[g][nb][3]);
      }
      #pragma unroll
      for (int ks=0; ks<2; ++ks){
        u32 a0 = pk[2*ks][0],   a1 = pk[2*ks][1];
        u32 b0 = pk[2*ks+1][0], b1 = pk[2*ks+1][1];
        asm("v_permlane32_swap_b32 %0, %1" : "+v"(a0), "+v"(b0));
        asm("v_permlane32_swap_b32 %0, %1" : "+v"(a1), "+v"(b1));
        asm("v_permlane16_swap_b32 %0, %1" : "+v"(a0), "+v"(b0));
        asm("v_permlane16_swap_b32 %0, %1" : "+v"(a1), "+v"(b1));
        union { u32 u[4]; short8 s; } cvt;
        cvt.u[0] = a0; cvt.u[1] = a1; cvt.u[2] = b0; cvt.u[3] = b1;
        apg[g][ks] = cvt.s;
      }
    }

    // O += P V  (V-frags read once, shared by both q-groups)
    __builtin_amdgcn_s_setprio(1);
    #pragma unroll
    for (int ks=0;ks<2;ks++){
      #pragma unroll
      for (int hb=0;hb<4;hb++){
        const int vrow = hb*16 + l15;
        short8 bv = *(const short8*)(VsC + vrow*128 + (((ks*4 + l4) ^ swz) << 4));
        oacc[0][hb] = __builtin_amdgcn_mfma_f32_16x16x32_bf16(apg[0][ks], bv, oacc[0][hb], 0,0,0);
        oacc[1][hb] = __builtin_amdgcn_mfma_f32_16x16x32_bf16(apg[1][ks], bv, oacc[1][hb], 0,0,0);
      }
    }
    __builtin_amdgcn_s_setprio(0);
    __syncthreads();   // drains stage(kt+1) vmem + orders buffer reuse
  }

  // in-wave row-sum reduce (every lane -> full partial sum for q = g*16+l15)
  #pragma unroll
  for (int g=0; g<2; ++g){
    lr[g] += __shfl_xor(lr[g], 16, 64);
    lr[g] += __shfl_xor(lr[g], 32, 64);
  }

  // cross-half combine through dead stage LDS
  char*  scr  = (char*)Ks;                     // 32KB: 4 pairs x 8KB
  float* lscr = (float*)Vs;                    // 128 floats
  if (half == 1){
    #pragma unroll
    for (int g=0; g<2; ++g)
      #pragma unroll
      for (int hb=0;hb<4;hb++)
        *(f32x4*)(scr + pair*8192 + (g*4+hb)*1024 + lane*16) = oacc[g][hb];
    if (lane < 16){
      lscr[pair*32 + lane]      = lr[0];
      lscr[pair*32 + 16 + lane] = lr[1];
    }
  }
  __syncthreads();

  if (half == 0){
    const int b = bh >> 4, h = bh & 15;
    #pragma unroll
    for (int g=0; g<2; ++g){
      const float lg = lr[g] + lscr[pair*32 + g*16 + l15];
      float inv[4];
      #pragma unroll
      for (int r=0;r<4;r++)
        inv[r] = 1.0f / __shfl(lg, 4*l4 + r, 64);
      #pragma unroll
      for (int hb=0;hb<4;hb++){
        f32x4 o2 = *(const f32x4*)(scr + pair*8192 + (g*4+hb)*1024 + lane*16);
        #pragma unroll
        for (int r=0;r<4;r++){
          const int si = qb*128 + pair*32 + g*16 + 4*l4 + r;
          const float v = (oacc[g][hb][r] + o2[r]) * inv[r];
          Og[(((size_t)(b*S + si))*H + h)*HD + hb*16 + l15] = f2bf(v);
        }
      }
    }
  }
}

extern "C" void kernel_launch(void* const* d_in, const int* in_sizes, int n_in,
                              void* d_out, int out_size, void* d_ws, size_t ws_size,
                              hipStream_t stream) {
  const float* x  = (const float*)d_in[0];
  const float* Wq = (const float*)d_in[1];
  const float* bq = (const float*)d_in[2];
  const float* Wk = (const float*)d_in[3];
  const float* bk = (const float*)d_in[4];
  const float* Wv = (const float*)d_in[5];
  const float* bv = (const float*)d_in[6];
  const float* Wo = (const float*)d_in[7];
  const float* bo = (const float*)d_in[8];

  char* ws = (char*)d_ws;
  // layout (bytes): xb 0..8M | Wb 8M..16M (Wq,Wk,Wv,Wo) | Q 16M | K 24M | Vt 32M | AO 40M..48M
  u16* xb  = (u16*)(ws);
  u16* Wb  = (u16*)(ws + (size_t)8*1024*1024);
  u16* QKV = (u16*)(ws + (size_t)16*1024*1024);
  u16* AO  = (u16*)(ws + (size_t)40*1024*1024);
  float* out = (float*)d_out;

  cast_all<<<8192, 256, 0, stream>>>(x, Wq, Wk, Wv, Wo, xb, Wb);

  dim3 g1(8, 32, 3);
  gemm_qkv<<<g1, 256, 0, stream>>>(xb, Wb, bq, bk, bv, QKV);

  dim3 g2(16, 32, 1);
  attn_fwd<<<g2, 512, 0, stream>>>(QKV, QKV + 4194304, QKV + 2*4194304, AO);

  dim3 g3(8, 64, 1);
  gemm_out<<<g3, 256, 0, stream>>>(AO, Wb + 3145728, bo, out);
}